// Round 3
// baseline (4377.086 us; speedup 1.0000x reference)
//
#include <hip/hip_runtime.h>

typedef _Float16 f16;
typedef __attribute__((ext_vector_type(8))) _Float16 f16x8;
typedef __attribute__((ext_vector_type(4))) _Float16 f16x4;
typedef __attribute__((ext_vector_type(4))) float floatx4;

#define BB 512
#define AA 100
#define HH 1024
#define KX 96          // padded x-part of K (77 -> 96)
#define KTOT 1120      // 1024 (h) + 96 (x)
#define WSTR 1120      // Wcat row stride (f16 elems)

// ---------- prep kernels (one-time per launch) ----------

// Wcat[n][0..1023] = (f16) W_hh[n][k]
__global__ __launch_bounds__(256) void cast_whh_k(const float* __restrict__ whh,
                                                  f16* __restrict__ wcat) {
  int gid = blockIdx.x * 256 + threadIdx.x;   // 1,048,576 threads
  int n = gid >> 8, k4 = (gid & 255) << 2;
  float4 v = *(const float4*)(whh + (size_t)n * HH + k4);
  f16x4 o; o[0] = (f16)v.x; o[1] = (f16)v.y; o[2] = (f16)v.z; o[3] = (f16)v.w;
  *(f16x4*)(wcat + (size_t)n * WSTR + k4) = o;
}

// wembT[i][k] = W_emb[k][i] (i<77), b_emb[k] (i==77), 0 (i in [78,96))
__global__ __launch_bounds__(256) void cast_wembT_k(const float* __restrict__ wemb,
                                                    const float* __restrict__ bemb,
                                                    f16* __restrict__ wembT) {
  int gid = blockIdx.x * 256 + threadIdx.x;   // 96*1024 = 98,304 threads
  int i = gid >> 10, k = gid & 1023;
  float v = 0.f;
  if (i < 77) v = wemb[(size_t)k * 77 + i];
  else if (i == 77) v = bemb[k];
  wembT[gid] = (f16)v;
}

// W_comb = W_ih @ W_emb  (and bias col 77 -> bcomb), via MFMA.
// 64 blocks x 256 thr; block does 64 n-rows x 96 i-cols, K=1024.
__global__ __launch_bounds__(256) void prep_gemm_k(
    const float* __restrict__ wih, const f16* __restrict__ wembT,
    const float* __restrict__ bih, const float* __restrict__ bhh,
    f16* __restrict__ wcat, float* __restrict__ bcomb) {
  __shared__ __align__(16) f16 alds[64][1032];   // 132 KB, pad 8 f16
  int tid = threadIdx.x;
  int n0 = blockIdx.x * 64;
  for (int v = tid; v < 64 * 256; v += 256) {    // stage+cast W_ih rows
    int row = v >> 8, c4 = (v & 255) << 2;
    float4 s = *(const float4*)(wih + (size_t)(n0 + row) * HH + c4);
    f16x4 o; o[0] = (f16)s.x; o[1] = (f16)s.y; o[2] = (f16)s.z; o[3] = (f16)s.w;
    *(f16x4*)(&alds[row][c4]) = o;
  }
  __syncthreads();
  int w = tid >> 6, lane = tid & 63, lr = lane & 15, lk = lane >> 4;
  floatx4 acc[6];
  #pragma unroll
  for (int j = 0; j < 6; ++j) acc[j] = (floatx4){0.f, 0.f, 0.f, 0.f};
  for (int kc = 0; kc < 32; ++kc) {
    f16x8 a = *(const f16x8*)(&alds[w * 16 + lr][kc * 32 + lk * 8]);
    #pragma unroll
    for (int j = 0; j < 6; ++j) {
      f16x8 b = *(const f16x8*)(wembT + (size_t)(j * 16 + lr) * 1024 + kc * 32 + lk * 8);
      acc[j] = __builtin_amdgcn_mfma_f32_16x16x32_f16(a, b, acc[j], 0, 0, 0);
    }
  }
  #pragma unroll
  for (int j = 0; j < 6; ++j)
    #pragma unroll
    for (int r = 0; r < 4; ++r) {
      int n = n0 + w * 16 + lk * 4 + r;          // C/D: col=lane&15, row=(lane>>4)*4+r
      int i = j * 16 + lr;
      float v = acc[j][r];
      if (i == 77) bcomb[n] = v + bih[n] + bhh[n];
      wcat[(size_t)n * WSTR + 1024 + i] = (i == 77) ? (f16)0.f : (f16)v;
    }
}

// xh[(t*512+b)][i] = (f16) x[b, t, i]   (i<77; zero-pad to 96)
__global__ __launch_bounds__(256) void cast_x_k(const float* __restrict__ in,
                                                f16* __restrict__ xh) {
  int gid = blockIdx.x * 256 + threadIdx.x;  // 4,915,200 threads
  int row = gid / 96;
  int i = gid - row * 96;
  int t = row >> 9, b = row & 511;
  f16 v = (f16)0.f;
  if (i < 77) v = (f16)in[(size_t)b * 7700 + t * 77 + i];
  xh[(size_t)row * KX + i] = v;
}

__global__ __launch_bounds__(256) void init_hc_k(const float* __restrict__ h0,
                                                 const float* __restrict__ c0,
                                                 f16* __restrict__ h16,
                                                 float* __restrict__ cws) {
  int gid = blockIdx.x * 256 + threadIdx.x;  // 524,288 threads
  h16[gid] = (f16)h0[gid];
  cws[gid] = c0[gid];
}

// ---------- per-step fused GEMM + LSTM cell ----------

__device__ __forceinline__ float sigm(float x) { return 1.f / (1.f + __expf(-x)); }

// 1024 blocks x 256 thr (4 blocks/CU, 16 waves/CU). Tile: 32 batch x 16 h x 4
// gates; wave w = gate w. No A staging: h (1 MB) and W-slice are L2-resident;
// the 4 gate-waves read identical A addresses -> L1 hits.
__global__ __launch_bounds__(256, 4) void lstm_step_k(
    const f16* __restrict__ wcat, const float* __restrict__ bcomb,
    const f16* __restrict__ xh, const f16* __restrict__ hin,
    f16* __restrict__ hout, float* __restrict__ cws,
    float* __restrict__ outh, int t) {
  __shared__ float glds[4][32][18];     // 9,216 B gate-exchange
  int tid = threadIdx.x;
  int id = blockIdx.x;                  // 1024 blocks
  // XCD swizzle: per XCD working set = A (1.15 MB) + its 8 h-slices (1.15 MB).
  int xcd = id & 7, slot = id >> 3;     // slot 0..127
  int hb = xcd * 8 + (slot >> 4);       // 0..63
  int mb = slot & 15;                   // 0..15
  int m0 = mb * 32, h0 = hb * 16;

  int w = tid >> 6, lane = tid & 63, lr = lane & 15, lk = lane >> 4;

  const f16* ap0 = hin + (size_t)(m0 + lr) * HH + lk * 8;
  const f16* ap1 = ap0 + 16 * HH;
  const f16* bp  = wcat + (size_t)(w * HH + h0 + lr) * WSTR + lk * 8;

  floatx4 acc0 = {0.f, 0.f, 0.f, 0.f};
  floatx4 acc1 = acc0;

  #pragma unroll 8
  for (int kc = 0; kc < 32; ++kc) {     // h part: K = 1024
    f16x8 a0 = *(const f16x8*)(ap0 + kc * 32);
    f16x8 a1 = *(const f16x8*)(ap1 + kc * 32);
    f16x8 b  = *(const f16x8*)(bp + kc * 32);
    acc0 = __builtin_amdgcn_mfma_f32_16x16x32_f16(a0, b, acc0, 0, 0, 0);
    acc1 = __builtin_amdgcn_mfma_f32_16x16x32_f16(a1, b, acc1, 0, 0, 0);
  }
  const f16* xp0 = xh + ((size_t)(t * BB) + m0 + lr) * KX + lk * 8;
  const f16* xp1 = xp0 + 16 * KX;
  #pragma unroll
  for (int kc = 0; kc < 3; ++kc) {      // x part: K = 96
    f16x8 a0 = *(const f16x8*)(xp0 + kc * 32);
    f16x8 a1 = *(const f16x8*)(xp1 + kc * 32);
    f16x8 b  = *(const f16x8*)(bp + (32 + kc) * 32);
    acc0 = __builtin_amdgcn_mfma_f32_16x16x32_f16(a0, b, acc0, 0, 0, 0);
    acc1 = __builtin_amdgcn_mfma_f32_16x16x32_f16(a1, b, acc1, 0, 0, 0);
  }

  #pragma unroll
  for (int r = 0; r < 4; ++r) {         // C/D: col=lane&15, row=(lane>>4)*4+r
    glds[w][lk * 4 + r][lr]      = acc0[r];
    glds[w][16 + lk * 4 + r][lr] = acc1[r];
  }
  __syncthreads();

  // LSTM cell: gates i,f,g,o (PyTorch order)
  #pragma unroll
  for (int e = tid; e < 32 * 16; e += 256) {
    int row = e >> 4, col = e & 15;
    int bg = m0 + row, hc = h0 + col;
    float gi = glds[0][row][col] + bcomb[hc];
    float gf = glds[1][row][col] + bcomb[HH + hc];
    float gg = glds[2][row][col] + bcomb[2 * HH + hc];
    float go = glds[3][row][col] + bcomb[3 * HH + hc];
    float iv = sigm(gi), fv = sigm(gf), gv = tanhf(gg), ov = sigm(go);
    size_t idx = (size_t)bg * HH + hc;
    float cn = fv * cws[idx] + iv * gv;
    float hn = ov * tanhf(cn);
    cws[idx] = cn;
    outh[idx] = hn;
    hout[idx] = (f16)hn;
  }
}

// ---------- launch ----------

extern "C" void kernel_launch(void* const* d_in, const int* in_sizes, int n_in,
                              void* d_out, int out_size, void* d_ws, size_t ws_size,
                              hipStream_t stream) {
  const float* inputs = (const float*)d_in[0];
  const float* h0     = (const float*)d_in[1];
  const float* c0     = (const float*)d_in[2];
  const float* W_emb  = (const float*)d_in[3];
  const float* b_emb  = (const float*)d_in[4];
  const float* W_ih   = (const float*)d_in[5];
  const float* W_hh   = (const float*)d_in[6];
  const float* b_ih   = (const float*)d_in[7];
  const float* b_hh   = (const float*)d_in[8];
  float* out = (float*)d_out;

  char* ws = (char*)d_ws;
  f16*   Wcat  = (f16*)(ws);                 // 4096*1120*2   = 9,175,040
  f16*   xh    = (f16*)(ws + 9175040);       // 51200*96*2    = 9,830,400
  f16*   h16a  = (f16*)(ws + 19005440);      // 512*1024*2    = 1,048,576
  f16*   h16b  = (f16*)(ws + 20054016);      // 512*1024*2    = 1,048,576
  float* c_ws  = (float*)(ws + 21102592);    // 512*1024*4    = 2,097,152
  float* bcomb = (float*)(ws + 23199744);    // 4096*4        = 16,384
  f16*   wembT = (f16*)(ws + 23216128);      // 96*1024*2     = 196,608

  cast_whh_k  <<<4096, 256, 0, stream>>>(W_hh, Wcat);
  cast_wembT_k<<<384, 256, 0, stream>>>(W_emb, b_emb, wembT);
  prep_gemm_k <<<64, 256, 0, stream>>>(W_ih, wembT, b_ih, b_hh, Wcat, bcomb);
  cast_x_k    <<<19200, 256, 0, stream>>>(inputs, xh);
  init_hc_k   <<<2048, 256, 0, stream>>>(h0, c0, h16a, c_ws);

  for (int t = 0; t < 100; ++t) {
    const f16* hin = (t & 1) ? h16b : h16a;
    f16* hout      = (t & 1) ? h16a : h16b;
    lstm_step_k<<<1024, 256, 0, stream>>>(Wcat, bcomb, xh, hin, hout, c_ws,
                                          out + (size_t)t * BB * HH, t);
  }

  // h_f = h_99 (already fp32 in out[99]); c_f from workspace
  hipMemcpyAsync(out + (size_t)AA * BB * HH,
                 out + (size_t)99 * BB * HH,
                 (size_t)BB * HH * sizeof(float), hipMemcpyDeviceToDevice, stream);
  hipMemcpyAsync(out + (size_t)AA * BB * HH + (size_t)BB * HH,
                 c_ws,
                 (size_t)BB * HH * sizeof(float), hipMemcpyDeviceToDevice, stream);
}